// Round 7
// baseline (248.761 us; speedup 1.0000x reference)
//
#include <hip/hip_runtime.h>

#define G_VOX  68921      // 41^3
#define GMAX   68920      // last valid element index
#define NSEG   272        // 272 segments of 256 elements (phase-shifted); last few are padding
#define MWORDS 2176       // 32-bit sphere-mask words (69632 bits)
#define NEGV (-1.0e9f)
#define VTH  (-1.0e8f)

// 8-lane segment scan core: lanes l8=0..7 cooperatively scan one 256-element segment.
// smw points at the mask word for this segment's first quad (global word 8*s).
// Loads are per-lane PREDICATED on a nonzero mask nibble (skips ~30% of HBM lines;
// empty bits cluster) but remain 8 independent iterations with uses deferred to the
// second loop -> VMEM latency still pipelined (this was R3's gain; R0 chained them).
// Two-word 64-bit mask extract (field straddles a word when sh>28 — the R1 bug).
// 3-level xor-shuffle reduce; all 8 lanes return the group winner.
__device__ __forceinline__ void seg_scan8_core(
    const float* __restrict__ dens, const unsigned int* smw,
    int ebase, int sh, int eclamp, float& bv, int& bi)
{
    bv = NEGV; bi = ebase;
    float4       dq[8];
    unsigned int bq[8];
    unsigned int wprev = smw[0];
    #pragma unroll
    for (int q = 0; q < 8; ++q) {
        const int e = ebase + 32 * q;
        const unsigned int wnext = smw[q + 1];
        unsigned long long mw = ((unsigned long long)wnext << 32) | wprev;
        bq[q] = (unsigned int)(mw >> sh) & 0xFu;
        wprev = wnext;
        const int ec = (e + 3 <= GMAX) ? e : eclamp;       // branchless tail clamp
        if (bq[q]) dq[q] = *reinterpret_cast<const float4*>(dens + ec);
    }
    #pragma unroll
    for (int q = 0; q < 8; ++q) {
        if (bq[q]) {
            const int e = ebase + 32 * q;
            float v0 = (bq[q] & 1u) ? dq[q].x : NEGV;
            float v1 = (bq[q] & 2u) ? dq[q].y : NEGV;
            float v2 = (bq[q] & 4u) ? dq[q].z : NEGV;
            float v3 = (bq[q] & 8u) ? dq[q].w : NEGV;
            if (v0 > bv) { bv = v0; bi = e;     }   // ascending e + strict > = first occurrence
            if (v1 > bv) { bv = v1; bi = e + 1; }
            if (v2 > bv) { bv = v2; bi = e + 2; }
            if (v3 > bv) { bv = v3; bi = e + 3; }
        }
    }
    #pragma unroll
    for (int off = 4; off > 0; off >>= 1) {     // 3-level reduce within 8-lane group
        float ov = __shfl_xor(bv, off);
        int   oi = __shfl_xor(bi, off);
        if (ov > bv || (ov == bv && oi < bi)) { bv = ov; bi = oi; }
    }
}

// ---------------- Single fused kernel: mask-gen + density pass + K=4 pick/NMS ----------------
__global__ __launch_bounds__(512) void fused_peaks(
    const float* __restrict__ density,
    const float* __restrict__ gxyz,
    const float* __restrict__ Rm, const float* __restrict__ tp,
    const float* __restrict__ nmask,
    float* __restrict__ out)
{
    __shared__ unsigned int smask[MWORDS + 2];   // +2: suppression's 64-bit clears touch wd+1
    __shared__ float sval[NSEG];
    __shared__ int   sidx[NSEG];
    __shared__ int   flag[NSEG];
    __shared__ int   list[104];
    __shared__ int   nlist;
    __shared__ float rv[8];
    __shared__ int   ri[8];
    __shared__ float pval[4];
    __shared__ int   pidx[4];
    __shared__ int   pki[4], pkj[4], pkk[4];
    __shared__ float xs[41], ys[41], zs[41];     // per-axis grid coords (slab-identical)

    const int tid  = threadIdx.x;
    const int nc   = blockIdx.x;                 // 0..511
    const int n    = nc >> 2;
    const int h    = (-nc) & 3;                  // phase: nc*68921 + h == 0 (mod 4)
    const int lane = tid & 63;
    const int w    = tid >> 6;                   // wave 0..7
    const int s8   = lane >> 3;                  // local segment in group 0..7
    const int l8   = lane & 7;                   // lane-in-segment 0..7
    const float* dens = density + (size_t)nc * G_VOX;
    const int eclamp = h + ((GMAX - 3 - h) & ~3);  // last aligned in-bounds quad start

    // ---- stage axis coordinate tables (bit-exact: values read from gxyz itself;
    //      x depends only on i, y only on j, z only on k in the reference setup) ----
    if (tid < 41)                      xs[tid]       = gxyz[tid * 1681 * 3 + 0];
    else if (tid >= 64 && tid < 105)   ys[tid - 64]  = gxyz[(tid - 64) * 41 * 3 + 1];
    else if (tid >= 128 && tid < 169)  zs[tid - 128] = gxyz[(tid - 128) * 3 + 2];
    if (tid < 2) smask[MWORDS + tid] = 0u;
    for (int i = tid; i < NSEG; i += 512) flag[i] = 0;
    __syncthreads();

    // ---- in-block sphere mask gen: same f32 op chain as the reference test,
    //      ballot-assembled into LDS words (wave w, iter j covers word 16j+2w{,+1}) ----
    for (int j = 0; j < 136; ++j) {
        const int e = j * 512 + tid;
        bool bit = false;
        if (e < G_VOX) {
            const int i1 = e / 1681;
            const int r  = e - i1 * 1681;
            const int j1 = r / 41;
            const int k1 = r - j1 * 41;
            const float gx = xs[i1], gy = ys[j1], gz = zs[k1];
            const float s = __fadd_rn(__fadd_rn(__fmul_rn(gx, gx), __fmul_rn(gy, gy)),
                                      __fmul_rn(gz, gz));
            bit = (__fsqrt_rn(s) <= 6.0f);       // bit-matches np.linalg.norm <= 6
        }
        unsigned long long bal = __ballot(bit);
        if (lane == 0)       smask[e >> 5] = (unsigned int)bal;
        else if (lane == 32) smask[e >> 5] = (unsigned int)(bal >> 32);
    }
    __syncthreads();

    // ---- single density pass: wave w scans segment groups g = w, w+8, ... ----
    for (int g = w; g < 34; g += 8) {
        const int s = g * 8 + s8;                // 0..271, each exactly once
        const int ebase = h + 256 * s + 4 * l8;
        float bv; int bi;
        seg_scan8_core(dens, smask + 8 * s, ebase, h + 4 * l8, eclamp, bv, bi);
        if (l8 == 0) { sval[s] = bv; sidx[s] = bi; }
    }
    __syncthreads();

    // ---- K=4 rounds: table argmax + LDS-mask suppression + segment recompute ----
    for (int p = 0; p < 4; ++p) {
        float bv = -INFINITY;
        int   bi = 0x7FFFFFFF;
        if (tid < NSEG) { bv = sval[tid]; bi = sidx[tid]; }
        #pragma unroll
        for (int off = 32; off > 0; off >>= 1) {
            float ov = __shfl_down(bv, off);
            int   oi = __shfl_down(bi, off);
            if (ov > bv || (ov == bv && oi < bi)) { bv = ov; bi = oi; }
        }
        if (lane == 0) { rv[w] = bv; ri[w] = bi; }
        __syncthreads();
        if (w == 0) {
            bv = (lane < 8) ? rv[lane] : -INFINITY;
            bi = (lane < 8) ? ri[lane] : 0x7FFFFFFF;
            #pragma unroll
            for (int off = 4; off > 0; off >>= 1) {
                float ov = __shfl_down(bv, off);
                int   oi = __shfl_down(bi, off);
                if (ov > bv || (ov == bv && oi < bi)) { bv = ov; bi = oi; }
            }
            if (lane == 0) {
                pval[p] = bv;
                pidx[p] = bi;
                int pi = bi / 1681;
                int rr = bi - pi * 1681;
                int pj = rr / 41;
                pki[p] = pi; pkj[p] = pj; pkk[p] = rr - pj * 41;
                nlist = 0;
            }
        }
        __syncthreads();

        if (p < 3 && pval[p] > VTH) {
            // clear 7x7x7 Chebyshev cube bits in LDS mask; collect segments needing
            // recompute. A segment is stale ONLY if its stored winner lies inside the
            // cube (bits outside the cube are untouched, so its max is otherwise
            // unchanged). Every cube-overlapping segment is examined by >=1 column,
            // and the winner-in-cube condition is column-independent -> safe.
            if (tid < 49) {
                int di = tid / 7 - 3, dj = tid % 7 - 3;
                int ii = pki[p] + di, jj = pkj[p] + dj;
                if (ii >= 0 && ii <= 40 && jj >= 0 && jj <= 40) {
                    int k0 = pkk[p] - 3; if (k0 < 0)  k0 = 0;
                    int k1 = pkk[p] + 3; if (k1 > 40) k1 = 40;
                    int b0  = ii * 1681 + jj * 41 + k0;
                    int cnt = k1 - k0 + 1;
                    unsigned long long m = ((1ull << cnt) - 1ull) << (b0 & 31);
                    int w0 = b0 >> 5;
                    atomicAnd(&smask[w0], ~(unsigned int)m);
                    unsigned int hi = (unsigned int)(m >> 32);
                    if (hi) atomicAnd(&smask[w0 + 1], ~hi);
                    // phase-shifted segment ids containing this run
                    int s0 = (b0 > h) ? (b0 - h) >> 8 : 0;
                    int s1 = (b0 + cnt - 1 > h) ? (b0 + cnt - 1 - h) >> 8 : 0;
                    #pragma unroll
                    for (int t2 = 0; t2 < 2; ++t2) {
                        const int s = t2 ? s1 : s0;
                        if (t2 && s1 == s0) break;
                        // winner-in-cube test for segment s
                        int widx = sidx[s];
                        int wi = widx / 1681;
                        int wr = widx - wi * 1681;
                        int wj = wr / 41;
                        int wk = wr - wj * 41;
                        int ci = wi - pki[p]; if (ci < 0) ci = -ci;
                        int cj = wj - pkj[p]; if (cj < 0) cj = -cj;
                        int ck = wk - pkk[p]; if (ck < 0) ck = -ck;
                        if (ci <= 3 && cj <= 3 && ck <= 3) {
                            if (atomicMax(&flag[s], p + 1) < p + 1) {
                                int q = atomicAdd(&nlist, 1); list[q] = s;
                            }
                        }
                    }
                }
            }
            __syncthreads();
            // recompute flagged segments: one 8-lane group per list entry (64 segs/sweep)
            const int cnt = nlist;
            for (int base = 0; base < cnt; base += 64) {
                const int slot = base + w * 8 + s8;
                if (slot < cnt) {                // uniform within the 8-lane group
                    const int s = list[slot];
                    const int ebase = h + 256 * s + 4 * l8;
                    float bv2; int bi2;
                    seg_scan8_core(dens, smask + 8 * s, ebase, h + 4 * l8, eclamp, bv2, bi2);
                    if (l8 == 0) { sval[s] = bv2; sidx[s] = bi2; }
                }
            }
        }
        __syncthreads();
    }

    // ---- epilogue: one peak per thread ----
    if (tid < 4) {
        const int k   = tid;
        const float val = pval[k];
        const int   idx = pidx[k];
        const bool valid = val > VTH;
        float gx = 0.0f, gy = 0.0f, gz = 0.0f;
        if (valid) {
            gx = gxyz[idx * 3 + 0];
            gy = gxyz[idx * 3 + 1];
            gz = gxyz[idx * 3 + 2];
        }
        const float nm = nmask[n];
        const float* R = Rm + n * 9;
        const float* t = tp + n * 3;
        float wx = R[0] * gx + R[1] * gy + R[2] * gz + t[0];
        float wy = R[3] * gx + R[4] * gy + R[5] * gz + t[1];
        float wz = R[6] * gx + R[7] * gy + R[8] * gz + t[2];

        const size_t o3 = ((size_t)nc * 4 + k) * 3;
        out[o3 + 0] = gx * nm;                       // coords_local [1,128,4,4,3]
        out[o3 + 1] = gy * nm;
        out[o3 + 2] = gz * nm;
        out[6144 + o3 + 0] = wx * nm;                // coords_global
        out[6144 + o3 + 1] = wy * nm;
        out[6144 + o3 + 2] = wz * nm;
        const size_t o1 = (size_t)nc * 4 + k;
        out[12288 + o1] = (valid ? val : NEGV) * nm; // scores
        out[14336 + o1] = (valid && nm != 0.0f) ? 1.0f : 0.0f;  // mask
    }
}

extern "C" void kernel_launch(void* const* d_in, const int* in_sizes, int n_in,
                              void* d_out, int out_size, void* d_ws, size_t ws_size,
                              hipStream_t stream) {
    const float* density  = (const float*)d_in[0];  // [1,128,4,G] f32
    const float* grid_xyz = (const float*)d_in[1];  // [G,3] f32
    const float* Rm    = (const float*)d_in[4];     // [1,128,3,3] f32
    const float* tpos  = (const float*)d_in[5];     // [1,128,3] f32
    const float* nmask = (const float*)d_in[6];     // [1,128] f32
    float* out = (float*)d_out;                     // 16384 f32

    fused_peaks<<<dim3(512), dim3(512), 0, stream>>>(density, grid_xyz,
                                                     Rm, tpos, nmask, out);
}

// Round 8
// 233.892 us; speedup vs baseline: 1.0636x; 1.0636x over previous
//
#include <hip/hip_runtime.h>

#define G_VOX  68921      // 41^3
#define GMAX   68920      // last valid element index
#define NSEG   272        // 272 segments of 256 elements (phase-shifted); last few are padding
#define MWORDS 2176       // 32-bit sphere-mask words (69632 bits)
#define NEGV (-1.0e9f)
#define VTH  (-1.0e8f)

__device__ __forceinline__ bool sphere_bit(const float* __restrict__ gxyz, int e) {
    if (e >= G_VOX) return false;
    float gx = gxyz[e * 3 + 0];
    float gy = gxyz[e * 3 + 1];
    float gz = gxyz[e * 3 + 2];
    float s  = __fadd_rn(__fadd_rn(__fmul_rn(gx, gx), __fmul_rn(gy, gy)),
                         __fmul_rn(gz, gz));
    return (__fsqrt_rn(s) <= 6.0f);   // bit-matches np.linalg.norm(grid_xyz) <= 6
}

// ---------------- Kernel 0: sphere word-mask ----------------
__global__ __launch_bounds__(256) void build_mask(
    const float* __restrict__ gxyz, unsigned int* __restrict__ mask)
{
    int idx = blockIdx.x * 256 + threadIdx.x;    // 0..69631
    unsigned long long bal = __ballot(sphere_bit(gxyz, idx));
    int lane = threadIdx.x & 63;
    if (lane == 0)       mask[idx >> 5] = (unsigned int)bal;
    else if (lane == 32) mask[idx >> 5] = (unsigned int)(bal >> 32);
}

// 8-lane segment scan core: lanes l8=0..7 cooperatively scan one 256-element segment.
// smw points at the mask word for this segment's first quad (global word 8*s).
// Loads are per-lane PREDICATED on a nonzero mask nibble (skips ~30% of HBM lines;
// empty bits cluster) but remain 8 independent iterations with uses deferred to the
// second loop -> VMEM latency still pipelined (this was R3's gain; R0 chained them).
// Two-word 64-bit mask extract (field straddles a word when sh>28 — the R1 bug).
// 3-level xor-shuffle reduce; all 8 lanes return the group winner.
__device__ __forceinline__ void seg_scan8_core(
    const float* __restrict__ dens, const unsigned int* smw,
    int ebase, int sh, int eclamp, float& bv, int& bi)
{
    bv = NEGV; bi = ebase;
    float4       dq[8];
    unsigned int bq[8];
    unsigned int wprev = smw[0];
    #pragma unroll
    for (int q = 0; q < 8; ++q) {
        const int e = ebase + 32 * q;
        const unsigned int wnext = smw[q + 1];
        unsigned long long mw = ((unsigned long long)wnext << 32) | wprev;
        bq[q] = (unsigned int)(mw >> sh) & 0xFu;
        wprev = wnext;
        const int ec = (e + 3 <= GMAX) ? e : eclamp;       // branchless tail clamp
        if (bq[q]) dq[q] = *reinterpret_cast<const float4*>(dens + ec);
    }
    #pragma unroll
    for (int q = 0; q < 8; ++q) {
        if (bq[q]) {
            const int e = ebase + 32 * q;
            float v0 = (bq[q] & 1u) ? dq[q].x : NEGV;
            float v1 = (bq[q] & 2u) ? dq[q].y : NEGV;
            float v2 = (bq[q] & 4u) ? dq[q].z : NEGV;
            float v3 = (bq[q] & 8u) ? dq[q].w : NEGV;
            if (v0 > bv) { bv = v0; bi = e;     }   // ascending e + strict > = first occurrence
            if (v1 > bv) { bv = v1; bi = e + 1; }
            if (v2 > bv) { bv = v2; bi = e + 2; }
            if (v3 > bv) { bv = v3; bi = e + 3; }
        }
    }
    #pragma unroll
    for (int off = 4; off > 0; off >>= 1) {     // 3-level reduce within 8-lane group
        float ov = __shfl_xor(bv, off);
        int   oi = __shfl_xor(bi, off);
        if (ov > bv || (ov == bv && oi < bi)) { bv = ov; bi = oi; }
    }
}

// ---------------- Fused kernel: one density pass + K=4 pick/NMS, one block per nc ----------------
// 1024 threads (16 waves): 2 blocks/CU -> 32 waves/CU (full wave occupancy), doubling
// in-flight VMEM per CU vs the 512-thread version (R7 PMC: Occupancy 38%, hbm 7% ->
// latency/TLP-bound, not BW-bound).
__global__ __launch_bounds__(1024) void fused_peaks(
    const float* __restrict__ density,
    const float* __restrict__ gxyz,
    const unsigned int* __restrict__ maskg,
    const float* __restrict__ Rm, const float* __restrict__ tp,
    const float* __restrict__ nmask,
    float* __restrict__ out)
{
    __shared__ unsigned int smask[MWORDS + 2];   // +2: suppression's 64-bit clears touch wd+1
    __shared__ float sval[NSEG];
    __shared__ int   sidx[NSEG];
    __shared__ int   flag[NSEG];
    __shared__ int   list[104];
    __shared__ int   nlist;
    __shared__ float rv[16];
    __shared__ int   ri[16];
    __shared__ float pval[4];
    __shared__ int   pidx[4];
    __shared__ int   pki[4], pkj[4], pkk[4];

    const int tid  = threadIdx.x;
    const int nc   = blockIdx.x;                 // 0..511
    const int n    = nc >> 2;
    const int h    = (-nc) & 3;                  // phase: nc*68921 + h == 0 (mod 4)
    const int lane = tid & 63;
    const int w    = tid >> 6;                   // wave 0..15
    const int s8   = lane >> 3;                  // local segment in group 0..7
    const int l8   = lane & 7;                   // lane-in-segment 0..7
    const float* dens = density + (size_t)nc * G_VOX;
    const int eclamp = h + ((GMAX - 3 - h) & ~3);  // last aligned in-bounds quad start

    for (int i = tid; i < MWORDS + 2; i += 1024) smask[i] = (i < MWORDS) ? maskg[i] : 0u;
    for (int i = tid; i < NSEG; i += 1024) flag[i] = 0;
    __syncthreads();

    // ---- single density pass: wave w scans segment groups g = w, w+16, ... ----
    for (int g = w; g < 34; g += 16) {
        const int s = g * 8 + s8;                // 0..271, each exactly once
        const int ebase = h + 256 * s + 4 * l8;
        float bv; int bi;
        seg_scan8_core(dens, smask + 8 * s, ebase, h + 4 * l8, eclamp, bv, bi);
        if (l8 == 0) { sval[s] = bv; sidx[s] = bi; }
    }
    __syncthreads();

    // ---- K=4 rounds: table argmax + LDS-mask suppression + segment recompute ----
    for (int p = 0; p < 4; ++p) {
        float bv = -INFINITY;
        int   bi = 0x7FFFFFFF;
        if (tid < NSEG) { bv = sval[tid]; bi = sidx[tid]; }
        #pragma unroll
        for (int off = 32; off > 0; off >>= 1) {
            float ov = __shfl_down(bv, off);
            int   oi = __shfl_down(bi, off);
            if (ov > bv || (ov == bv && oi < bi)) { bv = ov; bi = oi; }
        }
        if (lane == 0) { rv[w] = bv; ri[w] = bi; }
        __syncthreads();
        if (w == 0) {
            bv = (lane < 16) ? rv[lane] : -INFINITY;
            bi = (lane < 16) ? ri[lane] : 0x7FFFFFFF;
            #pragma unroll
            for (int off = 8; off > 0; off >>= 1) {
                float ov = __shfl_down(bv, off);
                int   oi = __shfl_down(bi, off);
                if (ov > bv || (ov == bv && oi < bi)) { bv = ov; bi = oi; }
            }
            if (lane == 0) {
                pval[p] = bv;
                pidx[p] = bi;
                int pi = bi / 1681;
                int rr = bi - pi * 1681;
                int pj = rr / 41;
                pki[p] = pi; pkj[p] = pj; pkk[p] = rr - pj * 41;
                nlist = 0;
            }
        }
        __syncthreads();

        if (p < 3 && pval[p] > VTH) {
            // clear 7x7x7 Chebyshev cube bits in LDS mask; collect segments needing
            // recompute. A segment is stale ONLY if its stored winner lies inside the
            // cube (bits outside the cube are untouched, so its max is otherwise
            // unchanged). Every cube-overlapping segment is examined by >=1 column,
            // and the winner-in-cube condition is column-independent -> safe.
            if (tid < 49) {
                int di = tid / 7 - 3, dj = tid % 7 - 3;
                int ii = pki[p] + di, jj = pkj[p] + dj;
                if (ii >= 0 && ii <= 40 && jj >= 0 && jj <= 40) {
                    int k0 = pkk[p] - 3; if (k0 < 0)  k0 = 0;
                    int k1 = pkk[p] + 3; if (k1 > 40) k1 = 40;
                    int b0  = ii * 1681 + jj * 41 + k0;
                    int cnt = k1 - k0 + 1;
                    unsigned long long m = ((1ull << cnt) - 1ull) << (b0 & 31);
                    int w0 = b0 >> 5;
                    atomicAnd(&smask[w0], ~(unsigned int)m);
                    unsigned int hi = (unsigned int)(m >> 32);
                    if (hi) atomicAnd(&smask[w0 + 1], ~hi);
                    // phase-shifted segment ids containing this run
                    int s0 = (b0 > h) ? (b0 - h) >> 8 : 0;
                    int s1 = (b0 + cnt - 1 > h) ? (b0 + cnt - 1 - h) >> 8 : 0;
                    #pragma unroll
                    for (int t2 = 0; t2 < 2; ++t2) {
                        const int s = t2 ? s1 : s0;
                        if (t2 && s1 == s0) break;
                        // winner-in-cube test for segment s
                        int widx = sidx[s];
                        int wi = widx / 1681;
                        int wr = widx - wi * 1681;
                        int wj = wr / 41;
                        int wk = wr - wj * 41;
                        int ci = wi - pki[p]; if (ci < 0) ci = -ci;
                        int cj = wj - pkj[p]; if (cj < 0) cj = -cj;
                        int ck = wk - pkk[p]; if (ck < 0) ck = -ck;
                        if (ci <= 3 && cj <= 3 && ck <= 3) {
                            if (atomicMax(&flag[s], p + 1) < p + 1) {
                                int q = atomicAdd(&nlist, 1); list[q] = s;
                            }
                        }
                    }
                }
            }
            __syncthreads();
            // recompute flagged segments: one 8-lane group per list entry (128 segs/sweep)
            const int cnt = nlist;
            for (int base = 0; base < cnt; base += 128) {
                const int slot = base + w * 8 + s8;
                if (slot < cnt) {                // uniform within the 8-lane group
                    const int s = list[slot];
                    const int ebase = h + 256 * s + 4 * l8;
                    float bv2; int bi2;
                    seg_scan8_core(dens, smask + 8 * s, ebase, h + 4 * l8, eclamp, bv2, bi2);
                    if (l8 == 0) { sval[s] = bv2; sidx[s] = bi2; }
                }
            }
        }
        __syncthreads();
    }

    // ---- epilogue: one peak per thread ----
    if (tid < 4) {
        const int k   = tid;
        const float val = pval[k];
        const int   idx = pidx[k];
        const bool valid = val > VTH;
        float gx = 0.0f, gy = 0.0f, gz = 0.0f;
        if (valid) {
            gx = gxyz[idx * 3 + 0];
            gy = gxyz[idx * 3 + 1];
            gz = gxyz[idx * 3 + 2];
        }
        const float nm = nmask[n];
        const float* R = Rm + n * 9;
        const float* t = tp + n * 3;
        float wx = R[0] * gx + R[1] * gy + R[2] * gz + t[0];
        float wy = R[3] * gx + R[4] * gy + R[5] * gz + t[1];
        float wz = R[6] * gx + R[7] * gy + R[8] * gz + t[2];

        const size_t o3 = ((size_t)nc * 4 + k) * 3;
        out[o3 + 0] = gx * nm;                       // coords_local [1,128,4,4,3]
        out[o3 + 1] = gy * nm;
        out[o3 + 2] = gz * nm;
        out[6144 + o3 + 0] = wx * nm;                // coords_global
        out[6144 + o3 + 1] = wy * nm;
        out[6144 + o3 + 2] = wz * nm;
        const size_t o1 = (size_t)nc * 4 + k;
        out[12288 + o1] = (valid ? val : NEGV) * nm; // scores
        out[14336 + o1] = (valid && nm != 0.0f) ? 1.0f : 0.0f;  // mask
    }
}

extern "C" void kernel_launch(void* const* d_in, const int* in_sizes, int n_in,
                              void* d_out, int out_size, void* d_ws, size_t ws_size,
                              hipStream_t stream) {
    const float* density  = (const float*)d_in[0];  // [1,128,4,G] f32
    const float* grid_xyz = (const float*)d_in[1];  // [G,3] f32
    const float* Rm    = (const float*)d_in[4];     // [1,128,3,3] f32
    const float* tpos  = (const float*)d_in[5];     // [1,128,3] f32
    const float* nmask = (const float*)d_in[6];     // [1,128] f32
    float* out = (float*)d_out;                     // 16384 f32

    unsigned int* mask = (unsigned int*)d_ws;       // 8704 B

    build_mask<<<dim3(272), dim3(256), 0, stream>>>(grid_xyz, mask);
    fused_peaks<<<dim3(512), dim3(1024), 0, stream>>>(density, grid_xyz, mask,
                                                      Rm, tpos, nmask, out);
}

// Round 9
// 218.747 us; speedup vs baseline: 1.1372x; 1.0692x over previous
//
#include <hip/hip_runtime.h>

#define G_VOX  68921      // 41^3
#define GMAX   68920      // last valid element index
#define NSEG   272        // 272 segments of 256 elements (phase-shifted); last few are padding
#define MWORDS 2176       // 32-bit sphere-mask words (69632 bits)
#define NEGV (-1.0e9f)
#define VTH  (-1.0e8f)

__device__ __forceinline__ bool sphere_bit(const float* __restrict__ gxyz, int e) {
    if (e >= G_VOX) return false;
    float gx = gxyz[e * 3 + 0];
    float gy = gxyz[e * 3 + 1];
    float gz = gxyz[e * 3 + 2];
    float s  = __fadd_rn(__fadd_rn(__fmul_rn(gx, gx), __fmul_rn(gy, gy)),
                         __fmul_rn(gz, gz));
    return (__fsqrt_rn(s) <= 6.0f);   // bit-matches np.linalg.norm(grid_xyz) <= 6
}

// ---------------- Kernel 0: sphere word-mask ----------------
__global__ __launch_bounds__(256) void build_mask(
    const float* __restrict__ gxyz, unsigned int* __restrict__ mask)
{
    int idx = blockIdx.x * 256 + threadIdx.x;    // 0..69631
    unsigned long long bal = __ballot(sphere_bit(gxyz, idx));
    int lane = threadIdx.x & 63;
    if (lane == 0)       mask[idx >> 5] = (unsigned int)bal;
    else if (lane == 32) mask[idx >> 5] = (unsigned int)(bal >> 32);
}

// 8-lane segment scan core: lanes l8=0..7 cooperatively scan one 256-element segment.
// smw points at the mask word for this segment's first quad (global word 8*s).
// Loads are per-lane PREDICATED on a nonzero mask nibble (skips ~30% of HBM lines);
// 8 independent iterations with uses deferred to the second loop -> VMEM pipelined.
// Two-word 64-bit mask extract (field straddles a word when sh>28 — the R1 bug).
// 3-level xor-shuffle reduce; all 8 lanes return the group winner.
__device__ __forceinline__ void seg_scan8_core(
    const float* __restrict__ dens, const unsigned int* smw,
    int ebase, int sh, int eclamp, float& bv, int& bi)
{
    bv = NEGV; bi = ebase;
    float4       dq[8];
    unsigned int bq[8];
    unsigned int wprev = smw[0];
    #pragma unroll
    for (int q = 0; q < 8; ++q) {
        const int e = ebase + 32 * q;
        const unsigned int wnext = smw[q + 1];
        unsigned long long mw = ((unsigned long long)wnext << 32) | wprev;
        bq[q] = (unsigned int)(mw >> sh) & 0xFu;
        wprev = wnext;
        const int ec = (e + 3 <= GMAX) ? e : eclamp;       // branchless tail clamp
        if (bq[q]) dq[q] = *reinterpret_cast<const float4*>(dens + ec);
    }
    #pragma unroll
    for (int q = 0; q < 8; ++q) {
        if (bq[q]) {
            const int e = ebase + 32 * q;
            float v0 = (bq[q] & 1u) ? dq[q].x : NEGV;
            float v1 = (bq[q] & 2u) ? dq[q].y : NEGV;
            float v2 = (bq[q] & 4u) ? dq[q].z : NEGV;
            float v3 = (bq[q] & 8u) ? dq[q].w : NEGV;
            if (v0 > bv) { bv = v0; bi = e;     }   // ascending e + strict > = first occurrence
            if (v1 > bv) { bv = v1; bi = e + 1; }
            if (v2 > bv) { bv = v2; bi = e + 2; }
            if (v3 > bv) { bv = v3; bi = e + 3; }
        }
    }
    #pragma unroll
    for (int off = 4; off > 0; off >>= 1) {     // 3-level reduce within 8-lane group
        float ov = __shfl_xor(bv, off);
        int   oi = __shfl_xor(bi, off);
        if (ov > bv || (ov == bv && oi < bi)) { bv = ov; bi = oi; }
    }
}

// ---------------- Fused kernel: one density pass + single-wave K=4 NMS ----------------
// Scan uses all 8 waves (one barrier). NMS runs entirely in wave 0 with ZERO further
// barriers: a wave's LDS ops execute in program order (per-wave LDS FIFO), so lane-0
// writes / wave-internal atomics are visible to later reads without __syncthreads.
// Waves 1-7 exit after the barrier, freeing their SIMDs (R8 showed cross-wave
// barriers, not TLP, are the overhead: 1024-thr regressed).
__global__ __launch_bounds__(512) void fused_peaks(
    const float* __restrict__ density,
    const float* __restrict__ gxyz,
    const unsigned int* __restrict__ maskg,
    const float* __restrict__ Rm, const float* __restrict__ tp,
    const float* __restrict__ nmask,
    float* __restrict__ out)
{
    __shared__ unsigned int smask[MWORDS + 2];   // +2: suppression's 64-bit clears touch wd+1
    __shared__ float sval[NSEG];
    __shared__ int   sidx[NSEG];
    __shared__ int   flag[NSEG];
    __shared__ int   list[104];
    __shared__ int   nlist;
    __shared__ float pval[4];
    __shared__ int   pidx[4];

    const int tid  = threadIdx.x;
    const int nc   = blockIdx.x;                 // 0..511
    const int n    = nc >> 2;
    const int h    = (-nc) & 3;                  // phase: nc*68921 + h == 0 (mod 4)
    const int lane = tid & 63;
    const int w    = tid >> 6;                   // wave 0..7
    const int s8   = lane >> 3;                  // local segment in group 0..7
    const int l8   = lane & 7;                   // lane-in-segment 0..7
    const float* dens = density + (size_t)nc * G_VOX;
    const int eclamp = h + ((GMAX - 3 - h) & ~3);  // last aligned in-bounds quad start

    for (int i = tid; i < MWORDS + 2; i += 512) smask[i] = (i < MWORDS) ? maskg[i] : 0u;
    for (int i = tid; i < NSEG; i += 512) flag[i] = 0;
    __syncthreads();

    // ---- single density pass: wave w scans segment groups g = w, w+8, ... ----
    for (int g = w; g < 34; g += 8) {
        const int s = g * 8 + s8;                // 0..271, each exactly once
        const int ebase = h + 256 * s + 4 * l8;
        float bv; int bi;
        seg_scan8_core(dens, smask + 8 * s, ebase, h + 4 * l8, eclamp, bv, bi);
        if (l8 == 0) { sval[s] = bv; sidx[s] = bi; }
    }
    __syncthreads();                             // last barrier; waves 1-7 exit after this

    if (w == 0) {
        // ---- K=4 rounds, wave 0 only, barrier-free ----
        for (int p = 0; p < 4; ++p) {
            // 272-entry argmax: 4-5 entries per lane, then 6-level shuffle reduce
            float bv = -INFINITY;
            int   bi = 0x7FFFFFFF;
            for (int t = lane; t < NSEG; t += 64) {
                float v = sval[t]; int ix = sidx[t];
                if (v > bv || (v == bv && ix < bi)) { bv = v; bi = ix; }
            }
            #pragma unroll
            for (int off = 32; off > 0; off >>= 1) {
                float ov = __shfl_down(bv, off);
                int   oi = __shfl_down(bi, off);
                if (ov > bv || (ov == bv && oi < bi)) { bv = ov; bi = oi; }
            }
            const float pv = __shfl(bv, 0);      // broadcast winner to all lanes
            const int   px = __shfl(bi, 0);
            if (lane == 0) { pval[p] = pv; pidx[p] = px; nlist = 0; }
            const int pi = px / 1681;
            const int rr = px - pi * 1681;
            const int pj = rr / 41;
            const int pk = rr - pj * 41;

            if (p < 3 && pv > VTH) {
                // clear 7x7x7 Chebyshev cube bits; flag segments whose stored winner
                // lies inside the cube (only those can be stale). lanes 0..48 = columns.
                if (lane < 49) {
                    int di = lane / 7 - 3, dj = lane % 7 - 3;
                    int ii = pi + di, jj = pj + dj;
                    if (ii >= 0 && ii <= 40 && jj >= 0 && jj <= 40) {
                        int k0 = pk - 3; if (k0 < 0)  k0 = 0;
                        int k1 = pk + 3; if (k1 > 40) k1 = 40;
                        int b0  = ii * 1681 + jj * 41 + k0;
                        int cnt = k1 - k0 + 1;
                        unsigned long long m = ((1ull << cnt) - 1ull) << (b0 & 31);
                        int w0 = b0 >> 5;
                        atomicAnd(&smask[w0], ~(unsigned int)m);
                        unsigned int hi = (unsigned int)(m >> 32);
                        if (hi) atomicAnd(&smask[w0 + 1], ~hi);
                        // phase-shifted segment ids containing this run
                        int s0 = (b0 > h) ? (b0 - h) >> 8 : 0;
                        int s1 = (b0 + cnt - 1 > h) ? (b0 + cnt - 1 - h) >> 8 : 0;
                        #pragma unroll
                        for (int t2 = 0; t2 < 2; ++t2) {
                            const int s = t2 ? s1 : s0;
                            if (t2 && s1 == s0) break;
                            int widx = sidx[s];
                            int wi = widx / 1681;
                            int wr = widx - wi * 1681;
                            int wj = wr / 41;
                            int wk = wr - wj * 41;
                            int ci = wi - pi; if (ci < 0) ci = -ci;
                            int cj = wj - pj; if (cj < 0) cj = -cj;
                            int ck = wk - pk; if (ck < 0) ck = -ck;
                            if (ci <= 3 && cj <= 3 && ck <= 3) {
                                if (atomicMax(&flag[s], p + 1) < p + 1) {
                                    int q = atomicAdd(&nlist, 1); list[q] = s;
                                }
                            }
                        }
                    }
                }
                // wave-ordered LDS: atomics above complete before this read
                const int cnt = nlist;
                // recompute flagged segments: 8 groups -> 8 segments per sweep
                for (int base = 0; base < cnt; base += 8) {
                    const int slot = base + s8;
                    if (slot < cnt) {            // uniform within the 8-lane group
                        const int s = list[slot];
                        const int ebase = h + 256 * s + 4 * l8;
                        float bv2; int bi2;
                        seg_scan8_core(dens, smask + 8 * s, ebase, h + 4 * l8, eclamp, bv2, bi2);
                        if (l8 == 0) { sval[s] = bv2; sidx[s] = bi2; }
                    }
                }
            }
        }

        // ---- epilogue: one peak per lane (lanes 0..3) ----
        if (lane < 4) {
            const int k   = lane;
            const float val = pval[k];
            const int   idx = pidx[k];
            const bool valid = val > VTH;
            float gx = 0.0f, gy = 0.0f, gz = 0.0f;
            if (valid) {
                gx = gxyz[idx * 3 + 0];
                gy = gxyz[idx * 3 + 1];
                gz = gxyz[idx * 3 + 2];
            }
            const float nm = nmask[n];
            const float* R = Rm + n * 9;
            const float* t = tp + n * 3;
            float wx = R[0] * gx + R[1] * gy + R[2] * gz + t[0];
            float wy = R[3] * gx + R[4] * gy + R[5] * gz + t[1];
            float wz = R[6] * gx + R[7] * gy + R[8] * gz + t[2];

            const size_t o3 = ((size_t)nc * 4 + k) * 3;
            out[o3 + 0] = gx * nm;                       // coords_local [1,128,4,4,3]
            out[o3 + 1] = gy * nm;
            out[o3 + 2] = gz * nm;
            out[6144 + o3 + 0] = wx * nm;                // coords_global
            out[6144 + o3 + 1] = wy * nm;
            out[6144 + o3 + 2] = wz * nm;
            const size_t o1 = (size_t)nc * 4 + k;
            out[12288 + o1] = (valid ? val : NEGV) * nm; // scores
            out[14336 + o1] = (valid && nm != 0.0f) ? 1.0f : 0.0f;  // mask
        }
    }
}

extern "C" void kernel_launch(void* const* d_in, const int* in_sizes, int n_in,
                              void* d_out, int out_size, void* d_ws, size_t ws_size,
                              hipStream_t stream) {
    const float* density  = (const float*)d_in[0];  // [1,128,4,G] f32
    const float* grid_xyz = (const float*)d_in[1];  // [G,3] f32
    const float* Rm    = (const float*)d_in[4];     // [1,128,3,3] f32
    const float* tpos  = (const float*)d_in[5];     // [1,128,3] f32
    const float* nmask = (const float*)d_in[6];     // [1,128] f32
    float* out = (float*)d_out;                     // 16384 f32

    unsigned int* mask = (unsigned int*)d_ws;       // 8704 B

    build_mask<<<dim3(272), dim3(256), 0, stream>>>(grid_xyz, mask);
    fused_peaks<<<dim3(512), dim3(512), 0, stream>>>(density, grid_xyz, mask,
                                                     Rm, tpos, nmask, out);
}